// Round 1
// 1940.502 us; speedup vs baseline: 2.4570x; 2.4570x over previous
//
#include <hip/hip_runtime.h>
#include <hip/hip_bf16.h>

typedef __hip_bfloat16 bf16;
typedef __attribute__((ext_vector_type(8))) short bf16x8;   // 8 bf16 (4 VGPRs)
typedef __attribute__((ext_vector_type(4))) float f32x4;    // 4 fp32 acc

__device__ __forceinline__ float tof(bf16 v) { return __bfloat162float(v); }
__device__ __forceinline__ float ldf(const float* p) { return *p; }
__device__ __forceinline__ float ldf(const bf16* p) { return __bfloat162float(*p); }
__device__ __forceinline__ void stf(float* p, float v) { *p = v; }
__device__ __forceinline__ void stf(bf16* p, float v) { *p = __float2bfloat16(v); }

// async global->LDS, 16B per lane; LDS dest must be wave-uniform base (+lane*16 by HW)
__device__ __forceinline__ void gl2lds16(const void* g, void* l) {
    __builtin_amdgcn_global_load_lds((const __attribute__((address_space(1))) void*)g,
                                     (__attribute__((address_space(3))) void*)l, 16, 0, 0);
}

// x is (2, 8, 56, 56, 384) fp32; WS=(2,7,7), SS=(1,3,3), 12 heads x 32. Output fp32.
constexpr int TOK   = 50176;      // 2*8*56*56
constexpr int CCH   = 384;
constexpr int NELEM = TOK * CCH;  // 19267584

// window-token index m (= b_*98 + n) -> token row in original (b,d,h,w) order.
__device__ __forceinline__ int remap_row(int m) {
    int b_ = m / 98, n = m % 98;
    int b = b_ >> 8, wrem = b_ & 255;
    int dw = wrem >> 6, hw = (wrem >> 3) & 7, wwi = wrem & 7;
    int zd = n / 49, r = n % 49, zh = r / 7, zw = r % 7;
    int d = ((dw * 2 + zd) + 1) & 7;
    int h = hw * 7 + zh + 3; if (h >= 56) h -= 56;
    int w = wwi * 7 + zw + 3; if (w >= 56) w -= 56;
    return ((b * 8 + d) * 56 + h) * 56 + w;
}

// ---------------- LayerNorm (one wave per token), out bf16.
template <bool SRC_INPUT>
__global__ __launch_bounds__(256) void ln_kernel(const void* __restrict__ srcv,
                                                 const float* __restrict__ g,
                                                 const float* __restrict__ be,
                                                 bf16* __restrict__ dst) {
    int wave = threadIdx.x >> 6, lane = threadIdx.x & 63;
    int t = blockIdx.x * 4 + wave;
    int srcRow = SRC_INPUT ? remap_row(t) : t;
    float v[6];
    float s = 0.f, ss = 0.f;
#pragma unroll
    for (int j = 0; j < 6; ++j) {
        size_t idx = (size_t)srcRow * CCH + lane + 64 * j;
        v[j] = SRC_INPUT ? ((const float*)srcv)[idx] : tof(((const bf16*)srcv)[idx]);
        s += v[j];
        ss += v[j] * v[j];
    }
#pragma unroll
    for (int off = 32; off; off >>= 1) {
        s  += __shfl_xor(s, off, 64);
        ss += __shfl_xor(ss, off, 64);
    }
    float mean = s * (1.f / 384.f);
    float var  = ss * (1.f / 384.f) - mean * mean;
    float rstd = rsqrtf(var + 1e-5f);
    bf16* q = dst + (size_t)t * CCH;
#pragma unroll
    for (int j = 0; j < 6; ++j) {
        int c = lane + 64 * j;
        stf(q + c, (v[j] - mean) * rstd * g[c] + be[c]);
    }
}

// ---------------- fp32 weight -> bf16 hi/lo split (hi+lo ~= fp32 to 2^-17 rel)
__global__ __launch_bounds__(256) void cvt_split(const float* __restrict__ w,
                                                 bf16* __restrict__ hi,
                                                 bf16* __restrict__ lo, int n) {
    int i = blockIdx.x * 256 + threadIdx.x;
    if (i >= n) return;
    float f = w[i];
    bf16 h = __float2bfloat16(f);
    hi[i] = h;
    lo[i] = __float2bfloat16(f - __bfloat162float(h));
}

// ---------------- MFMA GEMM: acc[m,n] = sum_k A[m,k] * (Bh[n,k]+Bl[n,k]); fp32 accum.
// 128x128 tile, BK=32, 4 waves each owning 64x64 (4x4 fragments of 16x16x32 bf16 MFMA).
// LDS layout per tile: slot(kb,row) = kb*128 + (row ^ (kb<<1)), 16B slots (8 bf16, K-contig).
//   - staging is linear in slot index -> global_load_lds-compatible (linear dest)
//   - frag read: lanes 0..15 rows (2-way free), kb groups 0..3 banks b,b^8,b^16,b^24 -> conflict-free
// MODE 0: C = acc + bias                            (qkv; C bf16)
// MODE 1: C[remap(m)] = Xres[remap(m)] + acc + bias (proj+reverse+roll+residual)
// MODE 2: C = gelu(acc + bias)                      (fc1)
// MODE 4: C[m] = Xres[m] + acc + bias               (fc2+residual2; C fp32 final)
template <int MODE, typename CT, typename XT>
__global__ __launch_bounds__(256, 2) void gemm_mfma(const bf16* __restrict__ A, int lda,
                                                    const bf16* __restrict__ Bh,
                                                    const bf16* __restrict__ Bl, int ldb,
                                                    const float* __restrict__ bias,
                                                    CT* __restrict__ Cc, int ldc,
                                                    const XT* __restrict__ Xres,
                                                    int M, int K) {
    __shared__ short As[4096];   // 128 rows x 32 k, bf16 bits
    __shared__ short Bhs[4096];
    __shared__ short Bls[4096];
    const int tid  = threadIdx.x;
    const int lane = tid & 63;
    const int wv   = tid >> 6;
    const int wm   = wv >> 1, wn = wv & 1;
    const int bm = blockIdx.y * 128, bn = blockIdx.x * 128;
    const int kb = lane >> 4, r15 = lane & 15;

    f32x4 acc[4][4] = {};

    for (int k0 = 0; k0 < K; k0 += 32) {
        // ---- stage A (8KB) + Bh (8KB) + Bl (8KB): 2 passes x 256 lanes x 16B each
#pragma unroll
        for (int p = 0; p < 2; ++p) {
            const int i    = p * 256 + tid;
            const int kbb  = i >> 7;          // wave-uniform (64-lane chunks)
            const int rs   = i & 127;
            const int row  = rs ^ (kbb << 1); // inverse-swizzled source row
            const int koff = k0 + kbb * 8;
            int mrow = bm + row; if (mrow >= M) mrow = M - 1;  // clamp (dups ok, not written)
            const int lslot = (p * 256 + (wv << 6)) * 8;       // wave-uniform LDS base
            gl2lds16(A  + (size_t)mrow * lda + koff, &As[lslot]);
            gl2lds16(Bh + (size_t)(bn + row) * ldb + koff, &Bhs[lslot]);
            gl2lds16(Bl + (size_t)(bn + row) * ldb + koff, &Bls[lslot]);
        }
        __syncthreads();  // compiler drains vmcnt before barrier

        bf16x8 af[4];
#pragma unroll
        for (int im = 0; im < 4; ++im) {
            const int row = wm * 64 + im * 16 + r15;
            af[im] = *(const bf16x8*)&As[(kb * 128 + (row ^ (kb << 1))) * 8];
        }
#pragma unroll
        for (int in = 0; in < 4; ++in) {
            const int col = wn * 64 + in * 16 + r15;
            const int sl  = (kb * 128 + (col ^ (kb << 1))) * 8;
            const bf16x8 bh = *(const bf16x8*)&Bhs[sl];
            const bf16x8 bl = *(const bf16x8*)&Bls[sl];
#pragma unroll
            for (int im = 0; im < 4; ++im) {
                acc[im][in] = __builtin_amdgcn_mfma_f32_16x16x32_bf16(af[im], bh, acc[im][in], 0, 0, 0);
                acc[im][in] = __builtin_amdgcn_mfma_f32_16x16x32_bf16(af[im], bl, acc[im][in], 0, 0, 0);
            }
        }
        __syncthreads();
    }

    // ---- epilogue: C/D frag layout col=lane&15, row=(lane>>4)*4+reg (verified mapping)
#pragma unroll
    for (int im = 0; im < 4; ++im) {
        const int mb = bm + wm * 64 + im * 16 + (lane >> 4) * 4;
#pragma unroll
        for (int in = 0; in < 4; ++in) {
            const int c = bn + wn * 64 + in * 16 + r15;
            const float bv = bias[c];
#pragma unroll
            for (int r = 0; r < 4; ++r) {
                const int m = mb + r;
                if (m >= M) continue;
                float v = acc[im][in][r] + bv;
                if (MODE == 0) {
                    stf(Cc + (size_t)m * ldc + c, v);
                } else if (MODE == 1) {
                    size_t xi = (size_t)remap_row(m) * ldc + c;
                    stf(Cc + xi, ldf(Xres + xi) + v);
                } else if (MODE == 2) {
                    stf(Cc + (size_t)m * ldc + c,
                        0.5f * v * (1.f + erff(v * 0.70710678118654752f)));
                } else {  // MODE 4
                    size_t xi = (size_t)m * ldc + c;
                    stf(Cc + xi, ldf(Xres + xi) + v);
                }
            }
        }
    }
}

// ---------------- Attention: one block per (window-in-group, head). Unchanged this round.
__global__ __launch_bounds__(256) void attn_kernel(const bf16* __restrict__ qkv,
                                                   const float* __restrict__ rpb,
                                                   bf16* __restrict__ outw, int gbase) {
    __shared__ float qs[98 * 33];
    __shared__ float ks[98 * 33];
    __shared__ float sc[98 * 99];
    int bid = blockIdx.x;
    int head = bid % 12;
    int brel = bid / 12;
    int babs = gbase + brel;
    int tid = threadIdx.x;
    size_t rowbase = (size_t)brel * 98 * 1152 + head * 32;

    for (int i = tid; i < 98 * 32; i += 256) {
        int n = i >> 5, e = i & 31;
        qs[n * 33 + e] = tof(qkv[rowbase + (size_t)n * 1152 + e]) * 0.17677669529663687f;
        ks[n * 33 + e] = tof(qkv[rowbase + (size_t)n * 1152 + 384 + e]);
    }
    int wrem = babs & 255;
    int dw = wrem >> 6, hw = (wrem >> 3) & 7, wwi = wrem & 7;
    __syncthreads();

    for (int fl = tid; fl < 98 * 98; fl += 256) {
        int i = fl / 98, j = fl % 98;
        float s = 0.f;
#pragma unroll
        for (int kk = 0; kk < 32; ++kk) s += qs[i * 33 + kk] * ks[j * 33 + kk];
        int di = i / 49, ri = i % 49, hi = ri / 7, wi = ri % 7;
        int dj = j / 49, rj = j % 49, hj = rj / 7, wj = rj % 7;
        int idx = (di - dj + 1) * 169 + (hi - hj + 6) * 13 + (wi - wj + 6);
        s += rpb[(size_t)idx * 12 + head];
        int dpi = dw * 2 + di, hpi = hw * 7 + hi, wpi = wwi * 7 + wi;
        int dpj = dw * 2 + dj, hpj = hw * 7 + hj, wpj = wwi * 7 + wj;
        int ci = (dpi < 6 ? 0 : (dpi == 6 ? 1 : 2)) * 9 + (hpi < 49 ? 0 : (hpi < 53 ? 1 : 2)) * 3 +
                 (wpi < 49 ? 0 : (wpi < 53 ? 1 : 2));
        int cj = (dpj < 6 ? 0 : (dpj == 6 ? 1 : 2)) * 9 + (hpj < 49 ? 0 : (hpj < 53 ? 1 : 2)) * 3 +
                 (wpj < 49 ? 0 : (wpj < 53 ? 1 : 2));
        if (ci != cj) s -= 100.f;
        sc[i * 99 + j] = s;
    }
    __syncthreads();

    int wave = tid >> 6, lane = tid & 63;
    for (int r = wave; r < 98; r += 4) {
        float a0 = sc[r * 99 + lane];
        float a1 = (lane < 34) ? sc[r * 99 + 64 + lane] : -1e30f;
        float mx = fmaxf(a0, a1);
#pragma unroll
        for (int off = 32; off; off >>= 1) mx = fmaxf(mx, __shfl_xor(mx, off, 64));
        float e0 = __expf(a0 - mx);
        float e1 = (lane < 34) ? __expf(a1 - mx) : 0.f;
        float sm = e0 + e1;
#pragma unroll
        for (int off = 32; off; off >>= 1) sm += __shfl_xor(sm, off, 64);
        float inv = 1.f / sm;
        sc[r * 99 + lane] = e0 * inv;
        if (lane < 34) sc[r * 99 + 64 + lane] = e1 * inv;
    }
    __syncthreads();

    const bf16* vbase = qkv + rowbase + 768;
    for (int fl = tid; fl < 98 * 32; fl += 256) {
        int i = fl >> 5, e = fl & 31;
        float o = 0.f;
        for (int j = 0; j < 98; ++j) o += sc[i * 99 + j] * tof(vbase[(size_t)j * 1152 + e]);
        stf(outw + ((size_t)babs * 98 + i) * 384 + head * 32 + e, o);
    }
}

extern "C" void kernel_launch(void* const* d_in, const int* in_sizes, int n_in,
                              void* d_out, int out_size, void* d_ws, size_t ws_size,
                              hipStream_t stream) {
    const float* x      = (const float*)d_in[0];
    const float* n1w    = (const float*)d_in[1];
    const float* n1b    = (const float*)d_in[2];
    const float* qkv_w  = (const float*)d_in[3];
    const float* qkv_b  = (const float*)d_in[4];
    const float* rpb    = (const float*)d_in[5];
    const float* proj_w = (const float*)d_in[6];
    const float* proj_b = (const float*)d_in[7];
    const float* n2w    = (const float*)d_in[8];
    const float* n2b    = (const float*)d_in[9];
    const float* fc1_w  = (const float*)d_in[10];
    const float* fc1_b  = (const float*)d_in[11];
    const float* fc2_w  = (const float*)d_in[12];
    const float* fc2_b  = (const float*)d_in[13];

    // d_out (NELEM fp32 = 77 MB) doubles as staging:
    //   bytes [0, NELEM*2):        attn_out (bf16) — dead after proj
    //   bytes [NELEM*2, NELEM*4):  xn2 (bf16)      — consumed per-group before fc2 frontier
    bf16*  aout = (bf16*)d_out;
    bf16*  xn2  = (bf16*)((char*)d_out + (size_t)NELEM * 2);
    float* fout = (float*)d_out;

    // d_ws layout: [split weights (7.08 MB)] [rA = NELEM bf16] [rC chunk scratch]
    constexpr int QKV_WN  = 1152 * 384;
    constexpr int PROJ_WN = 384 * 384;
    constexpr int FC1_WN  = 1536 * 384;
    constexpr int FC2_WN  = 384 * 1536;
    bf16* qh  = (bf16*)d_ws;
    bf16* ql  = qh  + QKV_WN;
    bf16* ph  = ql  + QKV_WN;
    bf16* pl  = ph  + PROJ_WN;
    bf16* f1h = pl  + PROJ_WN;
    bf16* f1l = f1h + FC1_WN;
    bf16* f2h = f1l + FC1_WN;
    bf16* f2l = f2h + FC2_WN;
    bf16* rA  = f2l + FC2_WN;
    bf16* rC  = rA + (size_t)NELEM;
    size_t used    = (size_t)((char*)rC - (char*)d_ws);
    size_t rCbytes = (ws_size > used) ? ws_size - used : 0;

    // 0. split weights to bf16 hi/lo (per-launch; ~7 MB total, few µs)
    cvt_split<<<(QKV_WN  + 255) / 256, 256, 0, stream>>>(qkv_w,  qh,  ql,  QKV_WN);
    cvt_split<<<(PROJ_WN + 255) / 256, 256, 0, stream>>>(proj_w, ph,  pl,  PROJ_WN);
    cvt_split<<<(FC1_WN  + 255) / 256, 256, 0, stream>>>(fc1_w,  f1h, f1l, FC1_WN);
    cvt_split<<<(FC2_WN  + 255) / 256, 256, 0, stream>>>(fc2_w,  f2h, f2l, FC2_WN);

    // adaptive grouping (same as before)
    int W = 512;
    while (W > 1 && (size_t)W * 98 * 1152 * 2 > rCbytes) W >>= 1;
    int nqg = 512 / W;
    int ngm = 1;
    while (ngm < 1024 && (size_t)(TOK / ngm) * 1536 * 2 > rCbytes) ngm <<= 1;
    int Mt = TOK / ngm;

    dim3 blk(256);

    // 1. LN1 + shift + window partition: x -> rA (window-token order, bf16)
    ln_kernel<true><<<dim3(TOK / 4), blk, 0, stream>>>(x, n1w, n1b, rA);
    // 2. per group: QKV GEMM -> rC (bf16), attention -> aout (bf16)
    for (int g = 0; g < nqg; ++g) {
        int Mg = W * 98;
        gemm_mfma<0, bf16, float><<<dim3(1152 / 128, (Mg + 127) / 128), blk, 0, stream>>>(
            rA + (size_t)g * Mg * 384, 384, qh, ql, 384, qkv_b,
            rC, 1152, (const float*)nullptr, Mg, 384);
        attn_kernel<<<dim3(W * 12), blk, 0, stream>>>(rC, rpb, aout, g * W);
    }
    // 3. proj + window-reverse + roll + residual(x): aout -> rA (x1, bf16)
    gemm_mfma<1, bf16, float><<<dim3(384 / 128, TOK / 128), blk, 0, stream>>>(
        aout, 384, ph, pl, 384, proj_b, rA, 384, x, TOK, 384);
    // 4. LN2(x1=rA) -> xn2 (bf16, upper half of d_out)
    ln_kernel<false><<<dim3(TOK / 4), blk, 0, stream>>>(rA, n2w, n2b, xn2);
    // 5. MLP per token group: fc1+gelu -> rC (bf16 hid), fc2 + x1 residual -> fout (fp32 final)
    for (int g = 0; g < ngm; ++g) {
        size_t off = (size_t)g * Mt * 384;
        gemm_mfma<2, bf16, float><<<dim3(1536 / 128, (Mt + 127) / 128), blk, 0, stream>>>(
            xn2 + off, 384, f1h, f1l, 384, fc1_b, rC, 1536, (const float*)nullptr, Mt, 384);
        gemm_mfma<4, float, bf16><<<dim3(384 / 128, (Mt + 127) / 128), blk, 0, stream>>>(
            rC, 1536, f2h, f2l, 1536, fc2_b, fout + off, 384, rA + off, Mt, 1536);
    }
}

// Round 3
// 1214.977 us; speedup vs baseline: 3.9243x; 1.5972x over previous
//
#include <hip/hip_runtime.h>
#include <hip/hip_bf16.h>

typedef __hip_bfloat16 bf16;
typedef __attribute__((ext_vector_type(8))) short bf16x8;   // 8 bf16 (4 VGPRs)
typedef __attribute__((ext_vector_type(4))) float f32x4;    // 4 fp32 acc

__device__ __forceinline__ float tof(bf16 v) { return __bfloat162float(v); }
__device__ __forceinline__ float ldf(const float* p) { return *p; }
__device__ __forceinline__ float ldf(const bf16* p) { return __bfloat162float(*p); }
__device__ __forceinline__ void stf(float* p, float v) { *p = v; }
__device__ __forceinline__ void stf(bf16* p, float v) { *p = __float2bfloat16(v); }
__device__ __forceinline__ short bfbits(float v) {
    return (short)__builtin_bit_cast(unsigned short, __float2bfloat16(v));
}

// async global->LDS, 16B per lane; LDS dest must be wave-uniform base (+lane*16 by HW)
__device__ __forceinline__ void gl2lds16(const void* g, void* l) {
    __builtin_amdgcn_global_load_lds((const __attribute__((address_space(1))) void*)g,
                                     (__attribute__((address_space(3))) void*)l, 16, 0, 0);
}

// x is (2, 8, 56, 56, 384) fp32; WS=(2,7,7), SS=(1,3,3), 12 heads x 32. Output fp32.
constexpr int TOK   = 50176;      // 2*8*56*56
constexpr int CCH   = 384;
constexpr int NELEM = TOK * CCH;  // 19267584
constexpr int BT_N  = 8 * 12 * 98 * 112;  // fused bias+mask table floats (4.2 MB)

// window-token index m (= b_*98 + n) -> token row in original (b,d,h,w) order.
__device__ __forceinline__ int remap_row(int m) {
    int b_ = m / 98, n = m % 98;
    int b = b_ >> 8, wrem = b_ & 255;
    int dw = wrem >> 6, hw = (wrem >> 3) & 7, wwi = wrem & 7;
    int zd = n / 49, r = n % 49, zh = r / 7, zw = r % 7;
    int d = ((dw * 2 + zd) + 1) & 7;
    int h = hw * 7 + zh + 3; if (h >= 56) h -= 56;
    int w = wwi * 7 + zw + 3; if (w >= 56) w -= 56;
    return ((b * 8 + d) * 56 + h) * 56 + w;
}

// ---------------- LayerNorm (one wave per token), out bf16.
template <bool SRC_INPUT>
__global__ __launch_bounds__(256) void ln_kernel(const void* __restrict__ srcv,
                                                 const float* __restrict__ g,
                                                 const float* __restrict__ be,
                                                 bf16* __restrict__ dst) {
    int wave = threadIdx.x >> 6, lane = threadIdx.x & 63;
    int t = blockIdx.x * 4 + wave;
    int srcRow = SRC_INPUT ? remap_row(t) : t;
    float v[6];
    float s = 0.f, ss = 0.f;
#pragma unroll
    for (int j = 0; j < 6; ++j) {
        size_t idx = (size_t)srcRow * CCH + lane + 64 * j;
        v[j] = SRC_INPUT ? ((const float*)srcv)[idx] : tof(((const bf16*)srcv)[idx]);
        s += v[j];
        ss += v[j] * v[j];
    }
#pragma unroll
    for (int off = 32; off; off >>= 1) {
        s  += __shfl_xor(s, off, 64);
        ss += __shfl_xor(ss, off, 64);
    }
    float mean = s * (1.f / 384.f);
    float var  = ss * (1.f / 384.f) - mean * mean;
    float rstd = rsqrtf(var + 1e-5f);
    bf16* q = dst + (size_t)t * CCH;
#pragma unroll
    for (int j = 0; j < 6; ++j) {
        int c = lane + 64 * j;
        stf(q + c, (v[j] - mean) * rstd * g[c] + be[c]);
    }
}

// ---------------- fp32 weight -> bf16 hi/lo split (hi+lo ~= fp32 to 2^-17 rel)
__global__ __launch_bounds__(256) void cvt_split(const float* __restrict__ w,
                                                 bf16* __restrict__ hi,
                                                 bf16* __restrict__ lo, int n) {
    int i = blockIdx.x * 256 + threadIdx.x;
    if (i >= n) return;
    float f = w[i];
    bf16 h = __float2bfloat16(f);
    hi[i] = h;
    lo[i] = __float2bfloat16(f - __bfloat162float(h));
}

// ---------------- fused rel-pos-bias + shift-mask table:
// table[cls][head][i][j]; cls = (dw==3)*4 | (hw==7)*2 | (wwi==7); j in [98,112) = -1e30.
__global__ __launch_bounds__(256) void bias_precomp(const float* __restrict__ rpb,
                                                    float* __restrict__ table) {
    int bid = blockIdx.x;                 // cls*12 + head, 96 blocks
    int cls = bid / 12, head = bid % 12;
    int cd = (cls >> 2) & 1, ch = (cls >> 1) & 1, cw = cls & 1;
    for (int e = threadIdx.x; e < 98 * 112; e += 256) {
        int i = e / 112, j = e % 112;
        float v;
        if (j >= 98) {
            v = -1e30f;
        } else {
            int di = i / 49, ri = i % 49, hi = ri / 7, wi = ri % 7;
            int dj = j / 49, rj = j % 49, hj = rj / 7, wj = rj % 7;
            int idx = (di - dj + 1) * 169 + (hi - hj + 6) * 13 + (wi - wj + 6);
            v = rpb[(size_t)idx * 12 + head];
            int ci = (cd ? (1 + di) : 0) * 9 + (ch ? (hi < 4 ? 1 : 2) : 0) * 3 +
                     (cw ? (wi < 4 ? 1 : 2) : 0);
            int cj = (cd ? (1 + dj) : 0) * 9 + (ch ? (hj < 4 ? 1 : 2) : 0) * 3 +
                     (cw ? (wj < 4 ? 1 : 2) : 0);
            if (ci != cj) v -= 100.f;
        }
        table[(size_t)bid * 98 * 112 + e] = v;
    }
}

// ---------------- MFMA GEMM (unchanged, harness-verified round 1)
template <int MODE, typename CT, typename XT>
__global__ __launch_bounds__(256, 2) void gemm_mfma(const bf16* __restrict__ A, int lda,
                                                    const bf16* __restrict__ Bh,
                                                    const bf16* __restrict__ Bl, int ldb,
                                                    const float* __restrict__ bias,
                                                    CT* __restrict__ Cc, int ldc,
                                                    const XT* __restrict__ Xres,
                                                    int M, int K) {
    __shared__ short As[4096];   // 128 rows x 32 k, bf16 bits
    __shared__ short Bhs[4096];
    __shared__ short Bls[4096];
    const int tid  = threadIdx.x;
    const int lane = tid & 63;
    const int wv   = tid >> 6;
    const int wm   = wv >> 1, wn = wv & 1;
    const int bm = blockIdx.y * 128, bn = blockIdx.x * 128;
    const int kb = lane >> 4, r15 = lane & 15;

    f32x4 acc[4][4] = {};

    for (int k0 = 0; k0 < K; k0 += 32) {
#pragma unroll
        for (int p = 0; p < 2; ++p) {
            const int i    = p * 256 + tid;
            const int kbb  = i >> 7;
            const int rs   = i & 127;
            const int row  = rs ^ (kbb << 1);
            const int koff = k0 + kbb * 8;
            int mrow = bm + row; if (mrow >= M) mrow = M - 1;
            const int lslot = (p * 256 + (wv << 6)) * 8;
            gl2lds16(A  + (size_t)mrow * lda + koff, &As[lslot]);
            gl2lds16(Bh + (size_t)(bn + row) * ldb + koff, &Bhs[lslot]);
            gl2lds16(Bl + (size_t)(bn + row) * ldb + koff, &Bls[lslot]);
        }
        __syncthreads();

        bf16x8 af[4];
#pragma unroll
        for (int im = 0; im < 4; ++im) {
            const int row = wm * 64 + im * 16 + r15;
            af[im] = *(const bf16x8*)&As[(kb * 128 + (row ^ (kb << 1))) * 8];
        }
#pragma unroll
        for (int in = 0; in < 4; ++in) {
            const int col = wn * 64 + in * 16 + r15;
            const int sl  = (kb * 128 + (col ^ (kb << 1))) * 8;
            const bf16x8 bh = *(const bf16x8*)&Bhs[sl];
            const bf16x8 bl = *(const bf16x8*)&Bls[sl];
#pragma unroll
            for (int im = 0; im < 4; ++im) {
                acc[im][in] = __builtin_amdgcn_mfma_f32_16x16x32_bf16(af[im], bh, acc[im][in], 0, 0, 0);
                acc[im][in] = __builtin_amdgcn_mfma_f32_16x16x32_bf16(af[im], bl, acc[im][in], 0, 0, 0);
            }
        }
        __syncthreads();
    }

#pragma unroll
    for (int im = 0; im < 4; ++im) {
        const int mb = bm + wm * 64 + im * 16 + (lane >> 4) * 4;
#pragma unroll
        for (int in = 0; in < 4; ++in) {
            const int c = bn + wn * 64 + in * 16 + r15;
            const float bv = bias[c];
#pragma unroll
            for (int r = 0; r < 4; ++r) {
                const int m = mb + r;
                if (m >= M) continue;
                float v = acc[im][in][r] + bv;
                if (MODE == 0) {
                    stf(Cc + (size_t)m * ldc + c, v);
                } else if (MODE == 1) {
                    size_t xi = (size_t)remap_row(m) * ldc + c;
                    stf(Cc + xi, ldf(Xres + xi) + v);
                } else if (MODE == 2) {
                    stf(Cc + (size_t)m * ldc + c,
                        0.5f * v * (1.f + erff(v * 0.70710678118654752f)));
                } else {  // MODE 4
                    size_t xi = (size_t)m * ldc + c;
                    stf(Cc + xi, ldf(Xres + xi) + v);
                }
            }
        }
    }
}

// ---------------- MFMA attention: one block = one (window, head), 1 wave.
// 98 tokens padded to 112 (7 tiles of 16). hd=32 = one 16x16x32 K-step.
// S strip (16 q-rows x 112): 7 MFMA; fused bias/mask table adds -1e30 at j>=98 so
// padded exps are exactly 0. P (unnormalized exp, bf16) goes through a 4KB swizzled
// LDS tile to convert C-layout -> A-layout; V fragments gathered once from a 7KB
// row-major LDS tile. O = (P.V) * inv_rowsum.
__global__ __launch_bounds__(64) void attn_kernel(const bf16* __restrict__ qkv,
                                                  const float* __restrict__ bt,
                                                  bf16* __restrict__ outw, int gbase) {
    __shared__ short Vs[112 * 32];   // [j][e] row-major bf16 bits
    __shared__ short Ps[16 * 128];   // [i][j'] ; phys 8-block = (j>>3) ^ (i&7)
    const int bid  = blockIdx.x;
    const int head = bid % 12;
    const int brel = bid / 12;
    const int babs = gbase + brel;
    const int lane = threadIdx.x;
    const int g = lane >> 4, c15 = lane & 15;

    const size_t qbase = (size_t)brel * 98 * 1152 + head * 32;

    // stage V rows (clamp j>=98 -> 97: finite dups, killed by P=0)
#pragma unroll
    for (int it = 0; it < 7; ++it) {
        int c = it * 64 + lane;               // 0..447
        int j = c >> 2, e0 = (c & 3) * 8;
        int jc = j < 98 ? j : 97;
        *(bf16x8*)&Vs[j * 32 + e0] =
            *(const bf16x8*)(qkv + qbase + (size_t)jc * 1152 + 768 + e0);
    }
    // zero P tail: logical j-blocks 14,15 per row (j 112..127)
    if (lane < 32) {
        int i = lane >> 1, half = lane & 1;
        int pb = (14 + half) ^ (i & 7);
        *(bf16x8*)&Ps[i * 128 + pb * 8] = bf16x8{0, 0, 0, 0, 0, 0, 0, 0};
    }

    // Q / K fragments straight from global (A/B frag: row/col = lane&15, k = g*8+e)
    bf16x8 qf[7], kf[7];
#pragma unroll
    for (int t7 = 0; t7 < 7; ++t7) {
        int qi = t7 * 16 + c15; if (qi > 97) qi = 97;
        const bf16* rp = qkv + qbase + (size_t)qi * 1152 + g * 8;
        qf[t7] = *(const bf16x8*)rp;
        kf[t7] = *(const bf16x8*)(rp + 384);
    }
    __syncthreads();

    // V B-fragments, gathered once: vb[kb][t][e] = V[kb*32+g*8+e][t*16+c15]
    bf16x8 vb[4][2];
#pragma unroll
    for (int kb = 0; kb < 4; ++kb)
#pragma unroll
        for (int t = 0; t < 2; ++t) {
            bf16x8 f;
#pragma unroll
            for (int e = 0; e < 8; ++e) {
                int j = kb * 32 + g * 8 + e;
                int jv = j < 112 ? j : 111;          // clamped rows finite; P=0 there
                f[e] = Vs[jv * 32 + t * 16 + c15];
            }
            vb[kb][t] = f;
        }

    const int cls = ((((babs >> 6) & 3) == 3) ? 4 : 0) |
                    ((((babs >> 3) & 7) == 7) ? 2 : 0) |
                    (((babs & 7) == 7) ? 1 : 0);
    const float* btb = bt + (size_t)(cls * 12 + head) * 98 * 112;
    const float scale = 0.17677669529663687f;

#pragma unroll 1
    for (int it = 0; it < 7; ++it) {
        // S strip: 7 MFMA
        f32x4 s[7];
#pragma unroll
        for (int jt = 0; jt < 7; ++jt)
            s[jt] = __builtin_amdgcn_mfma_f32_16x16x32_bf16(qf[it], kf[jt],
                                                            f32x4{0, 0, 0, 0}, 0, 0, 0);
        // scale + bias/mask (C layout: row i = g*4+r, col j = jt*16+c15)
#pragma unroll
        for (int jt = 0; jt < 7; ++jt)
#pragma unroll
            for (int r = 0; r < 4; ++r) {
                int i = it * 16 + g * 4 + r; if (i > 97) i = 97;
                s[jt][r] = fmaf(s[jt][r], scale, btb[i * 112 + jt * 16 + c15]);
            }
        // row softmax: reduce over c15 (shfl within 16-lane group) + tiles
        float mx[4], inv[4];
#pragma unroll
        for (int r = 0; r < 4; ++r) {
            float m = s[0][r];
#pragma unroll
            for (int jt = 1; jt < 7; ++jt) m = fmaxf(m, s[jt][r]);
#pragma unroll
            for (int off = 8; off; off >>= 1) m = fmaxf(m, __shfl_xor(m, off, 64));
            mx[r] = m;
        }
#pragma unroll
        for (int jt = 0; jt < 7; ++jt)
#pragma unroll
            for (int r = 0; r < 4; ++r) s[jt][r] = __expf(s[jt][r] - mx[r]);
#pragma unroll
        for (int r = 0; r < 4; ++r) {
            float t = 0.f;
#pragma unroll
            for (int jt = 0; jt < 7; ++jt) t += s[jt][r];
#pragma unroll
            for (int off = 8; off; off >>= 1) t += __shfl_xor(t, off, 64);
            inv[r] = 1.f / t;
        }
        // P -> LDS (bf16, unnormalized); phys elem = i*128 + ((j>>3 ^ (i&7))<<3 | (j&7))
#pragma unroll
        for (int jt = 0; jt < 7; ++jt)
#pragma unroll
            for (int r = 0; r < 4; ++r) {
                int i = g * 4 + r;
                int j = jt * 16 + c15;
                int pj = ((((j >> 3) ^ (i & 7)) << 3)) | (j & 7);
                Ps[i * 128 + pj] = bfbits(s[jt][r]);
            }
        // PV: A-frag = P row c15, logical j-block kb*4+g -> phys block ^(c15&7)
        f32x4 o[2] = {f32x4{0, 0, 0, 0}, f32x4{0, 0, 0, 0}};
#pragma unroll
        for (int kb = 0; kb < 4; ++kb) {
            int pb = (kb * 4 + g) ^ (c15 & 7);
            bf16x8 pa = *(const bf16x8*)&Ps[c15 * 128 + pb * 8];
#pragma unroll
            for (int t = 0; t < 2; ++t)
                o[t] = __builtin_amdgcn_mfma_f32_16x16x32_bf16(pa, vb[kb][t], o[t], 0, 0, 0);
        }
        // store O (C layout: row i = g*4+r, col e = t*16+c15), normalize
#pragma unroll
        for (int t = 0; t < 2; ++t)
#pragma unroll
            for (int r = 0; r < 4; ++r) {
                int i = it * 16 + g * 4 + r;
                if (i < 98)
                    stf(outw + ((size_t)babs * 98 + i) * 384 + head * 32 + t * 16 + c15,
                        o[t][r] * inv[r]);
            }
    }
}

extern "C" void kernel_launch(void* const* d_in, const int* in_sizes, int n_in,
                              void* d_out, int out_size, void* d_ws, size_t ws_size,
                              hipStream_t stream) {
    const float* x      = (const float*)d_in[0];
    const float* n1w    = (const float*)d_in[1];
    const float* n1b    = (const float*)d_in[2];
    const float* qkv_w  = (const float*)d_in[3];
    const float* qkv_b  = (const float*)d_in[4];
    const float* rpb    = (const float*)d_in[5];
    const float* proj_w = (const float*)d_in[6];
    const float* proj_b = (const float*)d_in[7];
    const float* n2w    = (const float*)d_in[8];
    const float* n2b    = (const float*)d_in[9];
    const float* fc1_w  = (const float*)d_in[10];
    const float* fc1_b  = (const float*)d_in[11];
    const float* fc2_w  = (const float*)d_in[12];
    const float* fc2_b  = (const float*)d_in[13];

    // d_out (NELEM fp32 = 154 MB... actually NELEM*4 bytes) staging plan:
    //   bytes [0, 2N):    aout (bf16 attn out)  — written step 2, dead after proj (step 3)
    //   bytes [2N, 2N+4.2MB): btab (fp32 bias)  — written step 0, last read step 2 (attn)
    //   bytes [2N, 4N):   xn2 (bf16 LN2 out)    — written step 4 (AFTER btab dead),
    //                     consumed per-group by fc1 before fc2's fp32 write frontier
    bf16*  aout = (bf16*)d_out;
    float* btab = (float*)((char*)d_out + (size_t)NELEM * 2);
    bf16*  xn2  = (bf16*)((char*)d_out + (size_t)NELEM * 2);
    float* fout = (float*)d_out;

    // d_ws layout (round-1 footprint, 45.6 MB + rC): [split weights][rA][rC]
    constexpr int QKV_WN  = 1152 * 384;
    constexpr int PROJ_WN = 384 * 384;
    constexpr int FC1_WN  = 1536 * 384;
    constexpr int FC2_WN  = 384 * 1536;
    bf16* qh   = (bf16*)d_ws;
    bf16* ql   = qh  + QKV_WN;
    bf16* ph   = ql  + QKV_WN;
    bf16* pl   = ph  + PROJ_WN;
    bf16* f1h  = pl  + PROJ_WN;
    bf16* f1l  = f1h + FC1_WN;
    bf16* f2h  = f1l + FC1_WN;
    bf16* f2l  = f2h + FC2_WN;
    bf16* rA   = f2l + FC2_WN;
    bf16* rC   = rA + (size_t)NELEM;
    size_t used    = (size_t)((char*)rC - (char*)d_ws);
    size_t rCbytes = (ws_size > used) ? ws_size - used : 0;

    // 0. split weights + fused bias/mask table (btab lives in d_out upper half)
    cvt_split<<<(QKV_WN  + 255) / 256, 256, 0, stream>>>(qkv_w,  qh,  ql,  QKV_WN);
    cvt_split<<<(PROJ_WN + 255) / 256, 256, 0, stream>>>(proj_w, ph,  pl,  PROJ_WN);
    cvt_split<<<(FC1_WN  + 255) / 256, 256, 0, stream>>>(fc1_w,  f1h, f1l, FC1_WN);
    cvt_split<<<(FC2_WN  + 255) / 256, 256, 0, stream>>>(fc2_w,  f2h, f2l, FC2_WN);
    bias_precomp<<<96, 256, 0, stream>>>(rpb, btab);

    // adaptive grouping
    int W = 512;
    while (W > 1 && (size_t)W * 98 * 1152 * 2 > rCbytes) W >>= 1;
    int nqg = 512 / W;
    int ngm = 1;
    while (ngm < 1024 && (size_t)(TOK / ngm) * 1536 * 2 > rCbytes) ngm <<= 1;
    int Mt = TOK / ngm;

    dim3 blk(256);

    // 1. LN1 + shift + window partition: x -> rA (window-token order, bf16)
    ln_kernel<true><<<dim3(TOK / 4), blk, 0, stream>>>(x, n1w, n1b, rA);
    // 2. per group: QKV GEMM -> rC (bf16), attention -> aout (bf16)
    for (int g = 0; g < nqg; ++g) {
        int Mg = W * 98;
        gemm_mfma<0, bf16, float><<<dim3(1152 / 128, (Mg + 127) / 128), blk, 0, stream>>>(
            rA + (size_t)g * Mg * 384, 384, qh, ql, 384, qkv_b,
            rC, 1152, (const float*)nullptr, Mg, 384);
        attn_kernel<<<dim3(W * 12), dim3(64), 0, stream>>>(rC, btab, aout, g * W);
    }
    // 3. proj + window-reverse + roll + residual(x): aout -> rA (x1, bf16)
    gemm_mfma<1, bf16, float><<<dim3(384 / 128, TOK / 128), blk, 0, stream>>>(
        aout, 384, ph, pl, 384, proj_b, rA, 384, x, TOK, 384);
    // 4. LN2(x1=rA) -> xn2 (bf16, upper half of d_out; overwrites dead btab)
    ln_kernel<false><<<dim3(TOK / 4), blk, 0, stream>>>(rA, n2w, n2b, xn2);
    // 5. MLP per token group: fc1+gelu -> rC (bf16 hid), fc2 + x1 residual -> fout (fp32 final)
    for (int g = 0; g < ngm; ++g) {
        size_t off = (size_t)g * Mt * 384;
        gemm_mfma<2, bf16, float><<<dim3(1536 / 128, (Mt + 127) / 128), blk, 0, stream>>>(
            xn2 + off, 384, f1h, f1l, 384, fc1_b, rC, 1536, (const float*)nullptr, Mt, 384);
        gemm_mfma<4, float, bf16><<<dim3(384 / 128, (Mt + 127) / 128), blk, 0, stream>>>(
            rC, 1536, f2h, f2l, 1536, fc2_b, fout + off, 384, rA + off, Mt, 1536);
    }
}

// Round 4
// 1196.046 us; speedup vs baseline: 3.9864x; 1.0158x over previous
//
#include <hip/hip_runtime.h>
#include <hip/hip_bf16.h>

typedef __hip_bfloat16 bf16;
typedef __attribute__((ext_vector_type(8))) short bf16x8;   // 8 bf16 (4 VGPRs)
typedef __attribute__((ext_vector_type(4))) float f32x4;    // 4 fp32 acc

__device__ __forceinline__ float tof(bf16 v) { return __bfloat162float(v); }
__device__ __forceinline__ float ldf(const float* p) { return *p; }
__device__ __forceinline__ float ldf(const bf16* p) { return __bfloat162float(*p); }
__device__ __forceinline__ void stf(float* p, float v) { *p = v; }
__device__ __forceinline__ void stf(bf16* p, float v) { *p = __float2bfloat16(v); }
__device__ __forceinline__ short bfbits(float v) {
    return (short)__builtin_bit_cast(unsigned short, __float2bfloat16(v));
}

// async global->LDS, 16B per lane; LDS dest must be wave-uniform base (+lane*16 by HW)
__device__ __forceinline__ void gl2lds16(const void* g, void* l) {
    __builtin_amdgcn_global_load_lds((const __attribute__((address_space(1))) void*)g,
                                     (__attribute__((address_space(3))) void*)l, 16, 0, 0);
}

// x is (2, 8, 56, 56, 384) fp32; WS=(2,7,7), SS=(1,3,3), 12 heads x 32. Output fp32.
constexpr int TOK   = 50176;      // 2*8*56*56
constexpr int CCH   = 384;
constexpr int NELEM = TOK * CCH;  // 19267584
constexpr int BT_N  = 8 * 12 * 98 * 112;  // fused bias+mask table floats (4.2 MB)

// window-token index m (= b_*98 + n) -> token row in original (b,d,h,w) order.
__device__ __forceinline__ int remap_row(int m) {
    int b_ = m / 98, n = m % 98;
    int b = b_ >> 8, wrem = b_ & 255;
    int dw = wrem >> 6, hw = (wrem >> 3) & 7, wwi = wrem & 7;
    int zd = n / 49, r = n % 49, zh = r / 7, zw = r % 7;
    int d = ((dw * 2 + zd) + 1) & 7;
    int h = hw * 7 + zh + 3; if (h >= 56) h -= 56;
    int w = wwi * 7 + zw + 3; if (w >= 56) w -= 56;
    return ((b * 8 + d) * 56 + h) * 56 + w;
}

// ---------------- LayerNorm (one wave per token), out bf16.
template <bool SRC_INPUT>
__global__ __launch_bounds__(256) void ln_kernel(const void* __restrict__ srcv,
                                                 const float* __restrict__ g,
                                                 const float* __restrict__ be,
                                                 bf16* __restrict__ dst) {
    int wave = threadIdx.x >> 6, lane = threadIdx.x & 63;
    int t = blockIdx.x * 4 + wave;
    int srcRow = SRC_INPUT ? remap_row(t) : t;
    float v[6];
    float s = 0.f, ss = 0.f;
#pragma unroll
    for (int j = 0; j < 6; ++j) {
        size_t idx = (size_t)srcRow * CCH + lane + 64 * j;
        v[j] = SRC_INPUT ? ((const float*)srcv)[idx] : tof(((const bf16*)srcv)[idx]);
        s += v[j];
        ss += v[j] * v[j];
    }
#pragma unroll
    for (int off = 32; off; off >>= 1) {
        s  += __shfl_xor(s, off, 64);
        ss += __shfl_xor(ss, off, 64);
    }
    float mean = s * (1.f / 384.f);
    float var  = ss * (1.f / 384.f) - mean * mean;
    float rstd = rsqrtf(var + 1e-5f);
    bf16* q = dst + (size_t)t * CCH;
#pragma unroll
    for (int j = 0; j < 6; ++j) {
        int c = lane + 64 * j;
        stf(q + c, (v[j] - mean) * rstd * g[c] + be[c]);
    }
}

// ---------------- fp32 weight -> bf16 hi/lo split (hi+lo ~= fp32 to 2^-17 rel)
__global__ __launch_bounds__(256) void cvt_split(const float* __restrict__ w,
                                                 bf16* __restrict__ hi,
                                                 bf16* __restrict__ lo, int n) {
    int i = blockIdx.x * 256 + threadIdx.x;
    if (i >= n) return;
    float f = w[i];
    bf16 h = __float2bfloat16(f);
    hi[i] = h;
    lo[i] = __float2bfloat16(f - __bfloat162float(h));
}

// ---------------- fused rel-pos-bias + shift-mask table:
// table[cls][head][i][j]; cls = (dw==3)*4 | (hw==7)*2 | (wwi==7); j in [98,112) = -1e30.
__global__ __launch_bounds__(256) void bias_precomp(const float* __restrict__ rpb,
                                                    float* __restrict__ table) {
    int bid = blockIdx.x;                 // cls*12 + head, 96 blocks
    int cls = bid / 12, head = bid % 12;
    int cd = (cls >> 2) & 1, ch = (cls >> 1) & 1, cw = cls & 1;
    for (int e = threadIdx.x; e < 98 * 112; e += 256) {
        int i = e / 112, j = e % 112;
        float v;
        if (j >= 98) {
            v = -1e30f;
        } else {
            int di = i / 49, ri = i % 49, hi = ri / 7, wi = ri % 7;
            int dj = j / 49, rj = j % 49, hj = rj / 7, wj = rj % 7;
            int idx = (di - dj + 1) * 169 + (hi - hj + 6) * 13 + (wi - wj + 6);
            v = rpb[(size_t)idx * 12 + head];
            int ci = (cd ? (1 + di) : 0) * 9 + (ch ? (hi < 4 ? 1 : 2) : 0) * 3 +
                     (cw ? (wi < 4 ? 1 : 2) : 0);
            int cj = (cd ? (1 + dj) : 0) * 9 + (ch ? (hj < 4 ? 1 : 2) : 0) * 3 +
                     (cw ? (wj < 4 ? 1 : 2) : 0);
            if (ci != cj) v -= 100.f;
        }
        table[(size_t)bid * 98 * 112 + e] = v;
    }
}

// ---------------- MFMA GEMM: 128x128 tile, BK=64 (64 MFMA per barrier-pair).
// LDS layout per tile: slot(kg,row) = kg*128 + (row ^ (kg<<1)), 16B slots (8 bf16, K-contig),
// kg = 0..7 (8-k blocks). Staging linear in slot -> global_load_lds-compatible.
// Block-id XCD swizzle (m204 bijective): consecutive orig ids (sharing an A-panel, since
// bx varies fastest) get contiguous work on ONE XCD -> A-panel L2-resident per XCD.
// MODE 0: C = acc + bias; MODE 1: C[remap(m)] = Xres[remap(m)] + acc + bias
// MODE 2: C = gelu(acc+bias); MODE 4: C[m] = Xres[m] + acc + bias
template <int MODE, typename CT, typename XT>
__global__ __launch_bounds__(256, 2) void gemm_mfma(const bf16* __restrict__ A, int lda,
                                                    const bf16* __restrict__ Bh,
                                                    const bf16* __restrict__ Bl, int ldb,
                                                    const float* __restrict__ bias,
                                                    CT* __restrict__ Cc, int ldc,
                                                    const XT* __restrict__ Xres,
                                                    int M, int K) {
    __shared__ short As[8192];   // 128 rows x 64 k, bf16 bits (16KB)
    __shared__ short Bhs[8192];
    __shared__ short Bls[8192];
    const int tid  = threadIdx.x;
    const int lane = tid & 63;
    const int wv   = tid >> 6;
    const int wm   = wv >> 1, wn = wv & 1;
    // T1 XCD-aware bijective swizzle
    const int nwg  = gridDim.x * gridDim.y;
    const int orig = blockIdx.y * gridDim.x + blockIdx.x;
    const int q8 = nwg >> 3, r8 = nwg & 7;
    const int xcd = orig & 7, slot = orig >> 3;
    const int work = (xcd < r8) ? xcd * (q8 + 1) + slot
                                : r8 * (q8 + 1) + (xcd - r8) * q8 + slot;
    const int bm = (work / gridDim.x) * 128, bn = (work % gridDim.x) * 128;
    const int kb = lane >> 4, r15 = lane & 15;

    f32x4 acc[4][4] = {};

    for (int k0 = 0; k0 < K; k0 += 64) {
        // ---- stage A + Bh + Bl (16KB each): 4 passes x 256 lanes x 16B
#pragma unroll
        for (int p = 0; p < 4; ++p) {
            const int i    = p * 256 + tid;   // 0..1023
            const int kbb  = i >> 7;          // 0..7, wave-uniform (changes every 2 waves)
            const int rs   = i & 127;
            const int row  = rs ^ (kbb << 1); // inverse-swizzled source row
            const int koff = k0 + kbb * 8;
            int mrow = bm + row; if (mrow >= M) mrow = M - 1;  // clamp (dups ok, not written)
            const int lslot = (p * 256 + (wv << 6)) * 8;       // wave-uniform LDS base
            gl2lds16(A  + (size_t)mrow * lda + koff, &As[lslot]);
            gl2lds16(Bh + (size_t)(bn + row) * ldb + koff, &Bhs[lslot]);
            gl2lds16(Bl + (size_t)(bn + row) * ldb + koff, &Bls[lslot]);
        }
        __syncthreads();  // compiler drains vmcnt before barrier

#pragma unroll
        for (int ks = 0; ks < 2; ++ks) {
            const int kg = ks * 4 + kb;       // global 8-k block 0..7
            bf16x8 af[4];
#pragma unroll
            for (int im = 0; im < 4; ++im) {
                const int row = wm * 64 + im * 16 + r15;
                af[im] = *(const bf16x8*)&As[(kg * 128 + (row ^ (kg << 1))) * 8];
            }
#pragma unroll
            for (int in = 0; in < 4; ++in) {
                const int col = wn * 64 + in * 16 + r15;
                const int sl  = (kg * 128 + (col ^ (kg << 1))) * 8;
                const bf16x8 bh = *(const bf16x8*)&Bhs[sl];
                const bf16x8 bl = *(const bf16x8*)&Bls[sl];
#pragma unroll
                for (int im = 0; im < 4; ++im) {
                    acc[im][in] = __builtin_amdgcn_mfma_f32_16x16x32_bf16(af[im], bh, acc[im][in], 0, 0, 0);
                    acc[im][in] = __builtin_amdgcn_mfma_f32_16x16x32_bf16(af[im], bl, acc[im][in], 0, 0, 0);
                }
            }
        }
        __syncthreads();
    }

    // ---- epilogue: C/D frag layout col=lane&15, row=(lane>>4)*4+reg (verified mapping)
#pragma unroll
    for (int im = 0; im < 4; ++im) {
        const int mb = bm + wm * 64 + im * 16 + (lane >> 4) * 4;
#pragma unroll
        for (int in = 0; in < 4; ++in) {
            const int c = bn + wn * 64 + in * 16 + r15;
            const float bv = bias[c];
#pragma unroll
            for (int r = 0; r < 4; ++r) {
                const int m = mb + r;
                if (m >= M) continue;
                float v = acc[im][in][r] + bv;
                if (MODE == 0) {
                    stf(Cc + (size_t)m * ldc + c, v);
                } else if (MODE == 1) {
                    size_t xi = (size_t)remap_row(m) * ldc + c;
                    stf(Cc + xi, ldf(Xres + xi) + v);
                } else if (MODE == 2) {
                    stf(Cc + (size_t)m * ldc + c,
                        0.5f * v * (1.f + erff(v * 0.70710678118654752f)));
                } else {  // MODE 4
                    size_t xi = (size_t)m * ldc + c;
                    stf(Cc + xi, ldf(Xres + xi) + v);
                }
            }
        }
    }
}

// ---------------- MFMA attention (unchanged, harness-verified round 3): one block =
// one (window, head), 1 wave. 98 tokens padded to 112; hd=32 = one 16x16x32 K-step.
__global__ __launch_bounds__(64) void attn_kernel(const bf16* __restrict__ qkv,
                                                  const float* __restrict__ bt,
                                                  bf16* __restrict__ outw, int gbase) {
    __shared__ short Vs[112 * 32];   // [j][e] row-major bf16 bits
    __shared__ short Ps[16 * 128];   // [i][j'] ; phys 8-block = (j>>3) ^ (i&7)
    const int bid  = blockIdx.x;
    const int head = bid % 12;
    const int brel = bid / 12;
    const int babs = gbase + brel;
    const int lane = threadIdx.x;
    const int g = lane >> 4, c15 = lane & 15;

    const size_t qbase = (size_t)brel * 98 * 1152 + head * 32;

    // stage V rows (clamp j>=98 -> 97: finite dups, killed by P=0)
#pragma unroll
    for (int it = 0; it < 7; ++it) {
        int c = it * 64 + lane;               // 0..447
        int j = c >> 2, e0 = (c & 3) * 8;
        int jc = j < 98 ? j : 97;
        *(bf16x8*)&Vs[j * 32 + e0] =
            *(const bf16x8*)(qkv + qbase + (size_t)jc * 1152 + 768 + e0);
    }
    // zero P tail: logical j-blocks 14,15 per row (j 112..127)
    if (lane < 32) {
        int i = lane >> 1, half = lane & 1;
        int pb = (14 + half) ^ (i & 7);
        *(bf16x8*)&Ps[i * 128 + pb * 8] = bf16x8{0, 0, 0, 0, 0, 0, 0, 0};
    }

    // Q / K fragments straight from global (A/B frag: row/col = lane&15, k = g*8+e)
    bf16x8 qf[7], kf[7];
#pragma unroll
    for (int t7 = 0; t7 < 7; ++t7) {
        int qi = t7 * 16 + c15; if (qi > 97) qi = 97;
        const bf16* rp = qkv + qbase + (size_t)qi * 1152 + g * 8;
        qf[t7] = *(const bf16x8*)rp;
        kf[t7] = *(const bf16x8*)(rp + 384);
    }
    __syncthreads();

    // V B-fragments, gathered once: vb[kb][t][e] = V[kb*32+g*8+e][t*16+c15]
    bf16x8 vb[4][2];
#pragma unroll
    for (int kb = 0; kb < 4; ++kb)
#pragma unroll
        for (int t = 0; t < 2; ++t) {
            bf16x8 f;
#pragma unroll
            for (int e = 0; e < 8; ++e) {
                int j = kb * 32 + g * 8 + e;
                int jv = j < 112 ? j : 111;          // clamped rows finite; P=0 there
                f[e] = Vs[jv * 32 + t * 16 + c15];
            }
            vb[kb][t] = f;
        }

    const int cls = ((((babs >> 6) & 3) == 3) ? 4 : 0) |
                    ((((babs >> 3) & 7) == 7) ? 2 : 0) |
                    (((babs & 7) == 7) ? 1 : 0);
    const float* btb = bt + (size_t)(cls * 12 + head) * 98 * 112;
    const float scale = 0.17677669529663687f;

#pragma unroll 1
    for (int it = 0; it < 7; ++it) {
        // S strip: 7 MFMA
        f32x4 s[7];
#pragma unroll
        for (int jt = 0; jt < 7; ++jt)
            s[jt] = __builtin_amdgcn_mfma_f32_16x16x32_bf16(qf[it], kf[jt],
                                                            f32x4{0, 0, 0, 0}, 0, 0, 0);
        // scale + bias/mask (C layout: row i = g*4+r, col j = jt*16+c15)
#pragma unroll
        for (int jt = 0; jt < 7; ++jt)
#pragma unroll
            for (int r = 0; r < 4; ++r) {
                int i = it * 16 + g * 4 + r; if (i > 97) i = 97;
                s[jt][r] = fmaf(s[jt][r], scale, btb[i * 112 + jt * 16 + c15]);
            }
        // row softmax: reduce over c15 (shfl within 16-lane group) + tiles
        float mx[4], inv[4];
#pragma unroll
        for (int r = 0; r < 4; ++r) {
            float m = s[0][r];
#pragma unroll
            for (int jt = 1; jt < 7; ++jt) m = fmaxf(m, s[jt][r]);
#pragma unroll
            for (int off = 8; off; off >>= 1) m = fmaxf(m, __shfl_xor(m, off, 64));
            mx[r] = m;
        }
#pragma unroll
        for (int jt = 0; jt < 7; ++jt)
#pragma unroll
            for (int r = 0; r < 4; ++r) s[jt][r] = __expf(s[jt][r] - mx[r]);
#pragma unroll
        for (int r = 0; r < 4; ++r) {
            float t = 0.f;
#pragma unroll
            for (int jt = 0; jt < 7; ++jt) t += s[jt][r];
#pragma unroll
            for (int off = 8; off; off >>= 1) t += __shfl_xor(t, off, 64);
            inv[r] = 1.f / t;
        }
        // P -> LDS (bf16, unnormalized); phys elem = i*128 + ((j>>3 ^ (i&7))<<3 | (j&7))
#pragma unroll
        for (int jt = 0; jt < 7; ++jt)
#pragma unroll
            for (int r = 0; r < 4; ++r) {
                int i = g * 4 + r;
                int j = jt * 16 + c15;
                int pj = ((((j >> 3) ^ (i & 7)) << 3)) | (j & 7);
                Ps[i * 128 + pj] = bfbits(s[jt][r]);
            }
        // PV: A-frag = P row c15, logical j-block kb*4+g -> phys block ^(c15&7)
        f32x4 o[2] = {f32x4{0, 0, 0, 0}, f32x4{0, 0, 0, 0}};
#pragma unroll
        for (int kb = 0; kb < 4; ++kb) {
            int pb = (kb * 4 + g) ^ (c15 & 7);
            bf16x8 pa = *(const bf16x8*)&Ps[c15 * 128 + pb * 8];
#pragma unroll
            for (int t = 0; t < 2; ++t)
                o[t] = __builtin_amdgcn_mfma_f32_16x16x32_bf16(pa, vb[kb][t], o[t], 0, 0, 0);
        }
        // store O (C layout: row i = g*4+r, col e = t*16+c15), normalize
#pragma unroll
        for (int t = 0; t < 2; ++t)
#pragma unroll
            for (int r = 0; r < 4; ++r) {
                int i = it * 16 + g * 4 + r;
                if (i < 98)
                    stf(outw + ((size_t)babs * 98 + i) * 384 + head * 32 + t * 16 + c15,
                        o[t][r] * inv[r]);
            }
    }
}

extern "C" void kernel_launch(void* const* d_in, const int* in_sizes, int n_in,
                              void* d_out, int out_size, void* d_ws, size_t ws_size,
                              hipStream_t stream) {
    const float* x      = (const float*)d_in[0];
    const float* n1w    = (const float*)d_in[1];
    const float* n1b    = (const float*)d_in[2];
    const float* qkv_w  = (const float*)d_in[3];
    const float* qkv_b  = (const float*)d_in[4];
    const float* rpb    = (const float*)d_in[5];
    const float* proj_w = (const float*)d_in[6];
    const float* proj_b = (const float*)d_in[7];
    const float* n2w    = (const float*)d_in[8];
    const float* n2b    = (const float*)d_in[9];
    const float* fc1_w  = (const float*)d_in[10];
    const float* fc1_b  = (const float*)d_in[11];
    const float* fc2_w  = (const float*)d_in[12];
    const float* fc2_b  = (const float*)d_in[13];

    // d_out staging plan (NELEM*4 bytes):
    //   bytes [0, 2N):        aout (bf16 attn out) — written step 2, dead after proj (step 3)
    //   bytes [2N, 2N+4.2MB): btab (fp32 bias)     — written step 0, last read step 2 (attn)
    //   bytes [2N, 4N):       xn2 (bf16 LN2 out)   — written step 4 (AFTER btab dead),
    //                         consumed per-group by fc1 before fc2's fp32 write frontier
    bf16*  aout = (bf16*)d_out;
    float* btab = (float*)((char*)d_out + (size_t)NELEM * 2);
    bf16*  xn2  = (bf16*)((char*)d_out + (size_t)NELEM * 2);
    float* fout = (float*)d_out;

    // d_ws layout (round-1 footprint, 45.6 MB + rC): [split weights][rA][rC]
    constexpr int QKV_WN  = 1152 * 384;
    constexpr int PROJ_WN = 384 * 384;
    constexpr int FC1_WN  = 1536 * 384;
    constexpr int FC2_WN  = 384 * 1536;
    bf16* qh   = (bf16*)d_ws;
    bf16* ql   = qh  + QKV_WN;
    bf16* ph   = ql  + QKV_WN;
    bf16* pl   = ph  + PROJ_WN;
    bf16* f1h  = pl  + PROJ_WN;
    bf16* f1l  = f1h + FC1_WN;
    bf16* f2h  = f1l + FC1_WN;
    bf16* f2l  = f2h + FC2_WN;
    bf16* rA   = f2l + FC2_WN;
    bf16* rC   = rA + (size_t)NELEM;
    size_t used    = (size_t)((char*)rC - (char*)d_ws);
    size_t rCbytes = (ws_size > used) ? ws_size - used : 0;

    // 0. split weights + fused bias/mask table (btab lives in d_out upper half)
    cvt_split<<<(QKV_WN  + 255) / 256, 256, 0, stream>>>(qkv_w,  qh,  ql,  QKV_WN);
    cvt_split<<<(PROJ_WN + 255) / 256, 256, 0, stream>>>(proj_w, ph,  pl,  PROJ_WN);
    cvt_split<<<(FC1_WN  + 255) / 256, 256, 0, stream>>>(fc1_w,  f1h, f1l, FC1_WN);
    cvt_split<<<(FC2_WN  + 255) / 256, 256, 0, stream>>>(fc2_w,  f2h, f2l, FC2_WN);
    bias_precomp<<<96, 256, 0, stream>>>(rpb, btab);

    // adaptive grouping
    int W = 512;
    while (W > 1 && (size_t)W * 98 * 1152 * 2 > rCbytes) W >>= 1;
    int nqg = 512 / W;
    int ngm = 1;
    while (ngm < 1024 && (size_t)(TOK / ngm) * 1536 * 2 > rCbytes) ngm <<= 1;
    int Mt = TOK / ngm;

    dim3 blk(256);

    // 1. LN1 + shift + window partition: x -> rA (window-token order, bf16)
    ln_kernel<true><<<dim3(TOK / 4), blk, 0, stream>>>(x, n1w, n1b, rA);
    // 2. per group: QKV GEMM -> rC (bf16), attention -> aout (bf16)
    for (int g = 0; g < nqg; ++g) {
        int Mg = W * 98;
        gemm_mfma<0, bf16, float><<<dim3(1152 / 128, (Mg + 127) / 128), blk, 0, stream>>>(
            rA + (size_t)g * Mg * 384, 384, qh, ql, 384, qkv_b,
            rC, 1152, (const float*)nullptr, Mg, 384);
        attn_kernel<<<dim3(W * 12), dim3(64), 0, stream>>>(rC, btab, aout, g * W);
    }
    // 3. proj + window-reverse + roll + residual(x): aout -> rA (x1, bf16)
    gemm_mfma<1, bf16, float><<<dim3(384 / 128, TOK / 128), blk, 0, stream>>>(
        aout, 384, ph, pl, 384, proj_b, rA, 384, x, TOK, 384);
    // 4. LN2(x1=rA) -> xn2 (bf16, upper half of d_out; overwrites dead btab)
    ln_kernel<false><<<dim3(TOK / 4), blk, 0, stream>>>(rA, n2w, n2b, xn2);
    // 5. MLP per token group: fc1+gelu -> rC (bf16 hid), fc2 + x1 residual -> fout (fp32 final)
    for (int g = 0; g < ngm; ++g) {
        size_t off = (size_t)g * Mt * 384;
        gemm_mfma<2, bf16, float><<<dim3(1536 / 128, (Mt + 127) / 128), blk, 0, stream>>>(
            xn2 + off, 384, f1h, f1l, 384, fc1_b, rC, 1536, (const float*)nullptr, Mt, 384);
        gemm_mfma<4, float, bf16><<<dim3(384 / 128, (Mt + 127) / 128), blk, 0, stream>>>(
            rC, 1536, f2h, f2l, 1536, fc2_b, fout + off, 384, rA + off, Mt, 1536);
    }
}

// Round 5
// 1173.169 us; speedup vs baseline: 4.0641x; 1.0195x over previous
//
#include <hip/hip_runtime.h>
#include <hip/hip_bf16.h>

typedef __hip_bfloat16 bf16;
typedef __attribute__((ext_vector_type(8))) short bf16x8;   // 8 bf16 (4 VGPRs)
typedef __attribute__((ext_vector_type(4))) float f32x4;    // 4 fp32 acc

__device__ __forceinline__ float tof(bf16 v) { return __bfloat162float(v); }
__device__ __forceinline__ float ldf(const float* p) { return *p; }
__device__ __forceinline__ float ldf(const bf16* p) { return __bfloat162float(*p); }
__device__ __forceinline__ void stf(float* p, float v) { *p = v; }
__device__ __forceinline__ void stf(bf16* p, float v) { *p = __float2bfloat16(v); }
__device__ __forceinline__ short bfbits(float v) {
    return (short)__builtin_bit_cast(unsigned short, __float2bfloat16(v));
}

// async global->LDS, 16B per lane; LDS dest must be wave-uniform base (+lane*16 by HW)
__device__ __forceinline__ void gl2lds16(const void* g, void* l) {
    __builtin_amdgcn_global_load_lds((const __attribute__((address_space(1))) void*)g,
                                     (__attribute__((address_space(3))) void*)l, 16, 0, 0);
}

// x is (2, 8, 56, 56, 384) fp32; WS=(2,7,7), SS=(1,3,3), 12 heads x 32. Output fp32.
constexpr int TOK   = 50176;      // 2*8*56*56
constexpr int CCH   = 384;
constexpr int NELEM = TOK * CCH;  // 19267584
constexpr int BT_N  = 8 * 12 * 98 * 112;  // fused bias+mask table floats (4.2 MB)

// window-token index m (= b_*98 + n) -> token row in original (b,d,h,w) order.
__device__ __forceinline__ int remap_row(int m) {
    int b_ = m / 98, n = m % 98;
    int b = b_ >> 8, wrem = b_ & 255;
    int dw = wrem >> 6, hw = (wrem >> 3) & 7, wwi = wrem & 7;
    int zd = n / 49, r = n % 49, zh = r / 7, zw = r % 7;
    int d = ((dw * 2 + zd) + 1) & 7;
    int h = hw * 7 + zh + 3; if (h >= 56) h -= 56;
    int w = wwi * 7 + zw + 3; if (w >= 56) w -= 56;
    return ((b * 8 + d) * 56 + h) * 56 + w;
}

// ---------------- LayerNorm (one wave per token), out bf16.
template <bool SRC_INPUT>
__global__ __launch_bounds__(256) void ln_kernel(const void* __restrict__ srcv,
                                                 const float* __restrict__ g,
                                                 const float* __restrict__ be,
                                                 bf16* __restrict__ dst) {
    int wave = threadIdx.x >> 6, lane = threadIdx.x & 63;
    int t = blockIdx.x * 4 + wave;
    int srcRow = SRC_INPUT ? remap_row(t) : t;
    float v[6];
    float s = 0.f, ss = 0.f;
#pragma unroll
    for (int j = 0; j < 6; ++j) {
        size_t idx = (size_t)srcRow * CCH + lane + 64 * j;
        v[j] = SRC_INPUT ? ((const float*)srcv)[idx] : tof(((const bf16*)srcv)[idx]);
        s += v[j];
        ss += v[j] * v[j];
    }
#pragma unroll
    for (int off = 32; off; off >>= 1) {
        s  += __shfl_xor(s, off, 64);
        ss += __shfl_xor(ss, off, 64);
    }
    float mean = s * (1.f / 384.f);
    float var  = ss * (1.f / 384.f) - mean * mean;
    float rstd = rsqrtf(var + 1e-5f);
    bf16* q = dst + (size_t)t * CCH;
#pragma unroll
    for (int j = 0; j < 6; ++j) {
        int c = lane + 64 * j;
        stf(q + c, (v[j] - mean) * rstd * g[c] + be[c]);
    }
}

// ---------------- fp32 weight -> bf16 hi/lo split (hi+lo ~= fp32 to 2^-17 rel)
__global__ __launch_bounds__(256) void cvt_split(const float* __restrict__ w,
                                                 bf16* __restrict__ hi,
                                                 bf16* __restrict__ lo, int n) {
    int i = blockIdx.x * 256 + threadIdx.x;
    if (i >= n) return;
    float f = w[i];
    bf16 h = __float2bfloat16(f);
    hi[i] = h;
    lo[i] = __float2bfloat16(f - __bfloat162float(h));
}

// ---------------- fused rel-pos-bias + shift-mask table:
// table[cls][head][i][j]; cls = (dw==3)*4 | (hw==7)*2 | (wwi==7); j in [98,112) = -1e30.
__global__ __launch_bounds__(256) void bias_precomp(const float* __restrict__ rpb,
                                                    float* __restrict__ table) {
    int bid = blockIdx.x;                 // cls*12 + head, 96 blocks
    int cls = bid / 12, head = bid % 12;
    int cd = (cls >> 2) & 1, ch = (cls >> 1) & 1, cw = cls & 1;
    for (int e = threadIdx.x; e < 98 * 112; e += 256) {
        int i = e / 112, j = e % 112;
        float v;
        if (j >= 98) {
            v = -1e30f;
        } else {
            int di = i / 49, ri = i % 49, hi = ri / 7, wi = ri % 7;
            int dj = j / 49, rj = j % 49, hj = rj / 7, wj = rj % 7;
            int idx = (di - dj + 1) * 169 + (hi - hj + 6) * 13 + (wi - wj + 6);
            v = rpb[(size_t)idx * 12 + head];
            int ci = (cd ? (1 + di) : 0) * 9 + (ch ? (hi < 4 ? 1 : 2) : 0) * 3 +
                     (cw ? (wi < 4 ? 1 : 2) : 0);
            int cj = (cd ? (1 + dj) : 0) * 9 + (ch ? (hj < 4 ? 1 : 2) : 0) * 3 +
                     (cw ? (wj < 4 ? 1 : 2) : 0);
            if (ci != cj) v -= 100.f;
        }
        table[(size_t)bid * 98 * 112 + e] = v;
    }
}

// ---------------- MFMA GEMM: 128x128 tile, BK=32, DOUBLE-BUFFERED 2-phase pipeline:
// per iteration: STAGE(next tile -> buf^1) issued FIRST, then ds_read+MFMA on buf,
// then ONE __syncthreads (compiler drains vmcnt(0)+lgkmcnt there) -> HBM/L2 latency of
// tile t+1 hides under tile t's MFMAs (T3 minimum recipe, m248).
// LDS layout per tile: slot(kg,row) = kg*128 + (row ^ (kg<<1)), 16B slots (8 bf16).
// Block-id XCD swizzle (m204 bijective) keeps A-panels L2-resident per XCD.
// MODE 0: C = acc + bias; MODE 1: C[remap(m)] = Xres[remap(m)] + acc + bias
// MODE 2: C = gelu(acc+bias); MODE 4: C[m] = Xres[m] + acc + bias
template <int MODE, typename CT, typename XT>
__global__ __launch_bounds__(256, 2) void gemm_mfma(const bf16* __restrict__ A, int lda,
                                                    const bf16* __restrict__ Bh,
                                                    const bf16* __restrict__ Bl, int ldb,
                                                    const float* __restrict__ bias,
                                                    CT* __restrict__ Cc, int ldc,
                                                    const XT* __restrict__ Xres,
                                                    int M, int K) {
    __shared__ short As[2][4096];   // 2 x (128 rows x 32 k) bf16 bits = 16KB
    __shared__ short Bhs[2][4096];
    __shared__ short Bls[2][4096];
    const int tid  = threadIdx.x;
    const int lane = tid & 63;
    const int wv   = tid >> 6;
    const int wm   = wv >> 1, wn = wv & 1;
    // T1 XCD-aware bijective swizzle
    const int nwg  = gridDim.x * gridDim.y;
    const int orig = blockIdx.y * gridDim.x + blockIdx.x;
    const int q8 = nwg >> 3, r8 = nwg & 7;
    const int xcd = orig & 7, slot = orig >> 3;
    const int work = (xcd < r8) ? xcd * (q8 + 1) + slot
                                : r8 * (q8 + 1) + (xcd - r8) * q8 + slot;
    const int bm = (work / gridDim.x) * 128, bn = (work % gridDim.x) * 128;
    const int kb = lane >> 4, r15 = lane & 15;

    f32x4 acc[4][4] = {};

    // staging helper values (per-thread global row/col, fixed across iterations)
    const int i0   = tid, i1 = 256 + tid;
    const int kbb0 = i0 >> 7, kbb1 = i1 >> 7;
    const int row0 = (i0 & 127) ^ (kbb0 << 1);
    const int row1 = (i1 & 127) ^ (kbb1 << 1);
    int mrow0 = bm + row0; if (mrow0 >= M) mrow0 = M - 1;
    int mrow1 = bm + row1; if (mrow1 >= M) mrow1 = M - 1;
    const int ls0 = (0 * 256 + (wv << 6)) * 8;   // wave-uniform LDS slot bases
    const int ls1 = (1 * 256 + (wv << 6)) * 8;

#define STAGE(buf, k0)                                                              \
    do {                                                                            \
        gl2lds16(A  + (size_t)mrow0 * lda + (k0) + kbb0 * 8, &As[buf][ls0]);        \
        gl2lds16(Bh + (size_t)(bn + row0) * ldb + (k0) + kbb0 * 8, &Bhs[buf][ls0]); \
        gl2lds16(Bl + (size_t)(bn + row0) * ldb + (k0) + kbb0 * 8, &Bls[buf][ls0]); \
        gl2lds16(A  + (size_t)mrow1 * lda + (k0) + kbb1 * 8, &As[buf][ls1]);        \
        gl2lds16(Bh + (size_t)(bn + row1) * ldb + (k0) + kbb1 * 8, &Bhs[buf][ls1]); \
        gl2lds16(Bl + (size_t)(bn + row1) * ldb + (k0) + kbb1 * 8, &Bls[buf][ls1]); \
    } while (0)

    // prologue: stage tile 0
    STAGE(0, 0);
    __syncthreads();   // vmcnt(0) drained here

    const int nk = K >> 5;
    int cur = 0;
    for (int t = 0; t < nk; ++t) {
        if (t + 1 < nk) STAGE(cur ^ 1, (t + 1) * 32);   // issue next tile's loads first

        bf16x8 af[4];
#pragma unroll
        for (int im = 0; im < 4; ++im) {
            const int row = wm * 64 + im * 16 + r15;
            af[im] = *(const bf16x8*)&As[cur][(kb * 128 + (row ^ (kb << 1))) * 8];
        }
#pragma unroll
        for (int in = 0; in < 4; ++in) {
            const int col = wn * 64 + in * 16 + r15;
            const int sl  = (kb * 128 + (col ^ (kb << 1))) * 8;
            const bf16x8 bh = *(const bf16x8*)&Bhs[cur][sl];
            const bf16x8 bl = *(const bf16x8*)&Bls[cur][sl];
#pragma unroll
            for (int im = 0; im < 4; ++im) {
                acc[im][in] = __builtin_amdgcn_mfma_f32_16x16x32_bf16(af[im], bh, acc[im][in], 0, 0, 0);
                acc[im][in] = __builtin_amdgcn_mfma_f32_16x16x32_bf16(af[im], bl, acc[im][in], 0, 0, 0);
            }
        }
        __syncthreads();   // drains vmcnt(0) (next tile staged) + lgkm; one barrier/iter
        cur ^= 1;
    }
#undef STAGE

    // ---- epilogue: C/D frag layout col=lane&15, row=(lane>>4)*4+reg (verified mapping)
#pragma unroll
    for (int im = 0; im < 4; ++im) {
        const int mb = bm + wm * 64 + im * 16 + (lane >> 4) * 4;
#pragma unroll
        for (int in = 0; in < 4; ++in) {
            const int c = bn + wn * 64 + in * 16 + r15;
            const float bv = bias[c];
#pragma unroll
            for (int r = 0; r < 4; ++r) {
                const int m = mb + r;
                if (m >= M) continue;
                float v = acc[im][in][r] + bv;
                if (MODE == 0) {
                    stf(Cc + (size_t)m * ldc + c, v);
                } else if (MODE == 1) {
                    size_t xi = (size_t)remap_row(m) * ldc + c;
                    stf(Cc + xi, ldf(Xres + xi) + v);
                } else if (MODE == 2) {
                    // tanh-approx GELU (error vs erf-GELU <= ~1e-3, below bf16 hid rounding)
                    float u  = v * fmaf(0.0356774081f, v * v, 0.7978845608f);
                    float e  = __expf(2.f * u);
                    float th = 1.f - 2.f * __builtin_amdgcn_rcpf(e + 1.f);
                    stf(Cc + (size_t)m * ldc + c, 0.5f * v * (1.f + th));
                } else {  // MODE 4
                    size_t xi = (size_t)m * ldc + c;
                    stf(Cc + xi, ldf(Xres + xi) + v);
                }
            }
        }
    }
}

// ---------------- MFMA attention (unchanged, harness-verified round 3): one block =
// one (window, head), 1 wave. 98 tokens padded to 112; hd=32 = one 16x16x32 K-step.
__global__ __launch_bounds__(64) void attn_kernel(const bf16* __restrict__ qkv,
                                                  const float* __restrict__ bt,
                                                  bf16* __restrict__ outw, int gbase) {
    __shared__ short Vs[112 * 32];   // [j][e] row-major bf16 bits
    __shared__ short Ps[16 * 128];   // [i][j'] ; phys 8-block = (j>>3) ^ (i&7)
    const int bid  = blockIdx.x;
    const int head = bid % 12;
    const int brel = bid / 12;
    const int babs = gbase + brel;
    const int lane = threadIdx.x;
    const int g = lane >> 4, c15 = lane & 15;

    const size_t qbase = (size_t)brel * 98 * 1152 + head * 32;

    // stage V rows (clamp j>=98 -> 97: finite dups, killed by P=0)
#pragma unroll
    for (int it = 0; it < 7; ++it) {
        int c = it * 64 + lane;               // 0..447
        int j = c >> 2, e0 = (c & 3) * 8;
        int jc = j < 98 ? j : 97;
        *(bf16x8*)&Vs[j * 32 + e0] =
            *(const bf16x8*)(qkv + qbase + (size_t)jc * 1152 + 768 + e0);
    }
    // zero P tail: logical j-blocks 14,15 per row (j 112..127)
    if (lane < 32) {
        int i = lane >> 1, half = lane & 1;
        int pb = (14 + half) ^ (i & 7);
        *(bf16x8*)&Ps[i * 128 + pb * 8] = bf16x8{0, 0, 0, 0, 0, 0, 0, 0};
    }

    // Q / K fragments straight from global (A/B frag: row/col = lane&15, k = g*8+e)
    bf16x8 qf[7], kf[7];
#pragma unroll
    for (int t7 = 0; t7 < 7; ++t7) {
        int qi = t7 * 16 + c15; if (qi > 97) qi = 97;
        const bf16* rp = qkv + qbase + (size_t)qi * 1152 + g * 8;
        qf[t7] = *(const bf16x8*)rp;
        kf[t7] = *(const bf16x8*)(rp + 384);
    }
    __syncthreads();

    // V B-fragments, gathered once: vb[kb][t][e] = V[kb*32+g*8+e][t*16+c15]
    bf16x8 vb[4][2];
#pragma unroll
    for (int kb = 0; kb < 4; ++kb)
#pragma unroll
        for (int t = 0; t < 2; ++t) {
            bf16x8 f;
#pragma unroll
            for (int e = 0; e < 8; ++e) {
                int j = kb * 32 + g * 8 + e;
                int jv = j < 112 ? j : 111;          // clamped rows finite; P=0 there
                f[e] = Vs[jv * 32 + t * 16 + c15];
            }
            vb[kb][t] = f;
        }

    const int cls = ((((babs >> 6) & 3) == 3) ? 4 : 0) |
                    ((((babs >> 3) & 7) == 7) ? 2 : 0) |
                    (((babs & 7) == 7) ? 1 : 0);
    const float* btb = bt + (size_t)(cls * 12 + head) * 98 * 112;
    const float scale = 0.17677669529663687f;

#pragma unroll 1
    for (int it = 0; it < 7; ++it) {
        // S strip: 7 MFMA
        f32x4 s[7];
#pragma unroll
        for (int jt = 0; jt < 7; ++jt)
            s[jt] = __builtin_amdgcn_mfma_f32_16x16x32_bf16(qf[it], kf[jt],
                                                            f32x4{0, 0, 0, 0}, 0, 0, 0);
        // scale + bias/mask (C layout: row i = g*4+r, col j = jt*16+c15)
#pragma unroll
        for (int jt = 0; jt < 7; ++jt)
#pragma unroll
            for (int r = 0; r < 4; ++r) {
                int i = it * 16 + g * 4 + r; if (i > 97) i = 97;
                s[jt][r] = fmaf(s[jt][r], scale, btb[i * 112 + jt * 16 + c15]);
            }
        // row softmax: reduce over c15 (shfl within 16-lane group) + tiles
        float mx[4], inv[4];
#pragma unroll
        for (int r = 0; r < 4; ++r) {
            float m = s[0][r];
#pragma unroll
            for (int jt = 1; jt < 7; ++jt) m = fmaxf(m, s[jt][r]);
#pragma unroll
            for (int off = 8; off; off >>= 1) m = fmaxf(m, __shfl_xor(m, off, 64));
            mx[r] = m;
        }
#pragma unroll
        for (int jt = 0; jt < 7; ++jt)
#pragma unroll
            for (int r = 0; r < 4; ++r) s[jt][r] = __expf(s[jt][r] - mx[r]);
#pragma unroll
        for (int r = 0; r < 4; ++r) {
            float t = 0.f;
#pragma unroll
            for (int jt = 0; jt < 7; ++jt) t += s[jt][r];
#pragma unroll
            for (int off = 8; off; off >>= 1) t += __shfl_xor(t, off, 64);
            inv[r] = 1.f / t;
        }
        // P -> LDS (bf16, unnormalized); phys elem = i*128 + ((j>>3 ^ (i&7))<<3 | (j&7))
#pragma unroll
        for (int jt = 0; jt < 7; ++jt)
#pragma unroll
            for (int r = 0; r < 4; ++r) {
                int i = g * 4 + r;
                int j = jt * 16 + c15;
                int pj = ((((j >> 3) ^ (i & 7)) << 3)) | (j & 7);
                Ps[i * 128 + pj] = bfbits(s[jt][r]);
            }
        // PV: A-frag = P row c15, logical j-block kb*4+g -> phys block ^(c15&7)
        f32x4 o[2] = {f32x4{0, 0, 0, 0}, f32x4{0, 0, 0, 0}};
#pragma unroll
        for (int kb = 0; kb < 4; ++kb) {
            int pb = (kb * 4 + g) ^ (c15 & 7);
            bf16x8 pa = *(const bf16x8*)&Ps[c15 * 128 + pb * 8];
#pragma unroll
            for (int t = 0; t < 2; ++t)
                o[t] = __builtin_amdgcn_mfma_f32_16x16x32_bf16(pa, vb[kb][t], o[t], 0, 0, 0);
        }
        // store O (C layout: row i = g*4+r, col e = t*16+c15), normalize
#pragma unroll
        for (int t = 0; t < 2; ++t)
#pragma unroll
            for (int r = 0; r < 4; ++r) {
                int i = it * 16 + g * 4 + r;
                if (i < 98)
                    stf(outw + ((size_t)babs * 98 + i) * 384 + head * 32 + t * 16 + c15,
                        o[t][r] * inv[r]);
            }
    }
}

extern "C" void kernel_launch(void* const* d_in, const int* in_sizes, int n_in,
                              void* d_out, int out_size, void* d_ws, size_t ws_size,
                              hipStream_t stream) {
    const float* x      = (const float*)d_in[0];
    const float* n1w    = (const float*)d_in[1];
    const float* n1b    = (const float*)d_in[2];
    const float* qkv_w  = (const float*)d_in[3];
    const float* qkv_b  = (const float*)d_in[4];
    const float* rpb    = (const float*)d_in[5];
    const float* proj_w = (const float*)d_in[6];
    const float* proj_b = (const float*)d_in[7];
    const float* n2w    = (const float*)d_in[8];
    const float* n2b    = (const float*)d_in[9];
    const float* fc1_w  = (const float*)d_in[10];
    const float* fc1_b  = (const float*)d_in[11];
    const float* fc2_w  = (const float*)d_in[12];
    const float* fc2_b  = (const float*)d_in[13];

    // d_out staging plan (NELEM*4 bytes):
    //   bytes [0, 2N):        aout (bf16 attn out) — written step 2, dead after proj (step 3)
    //   bytes [2N, 2N+4.2MB): btab (fp32 bias)     — written step 0, last read step 2 (attn)
    //   bytes [2N, 4N):       xn2 (bf16 LN2 out)   — written step 4 (AFTER btab dead),
    //                         consumed per-group by fc1 before fc2's fp32 write frontier
    bf16*  aout = (bf16*)d_out;
    float* btab = (float*)((char*)d_out + (size_t)NELEM * 2);
    bf16*  xn2  = (bf16*)((char*)d_out + (size_t)NELEM * 2);
    float* fout = (float*)d_out;

    // d_ws layout (round-1 footprint, 45.6 MB + rC): [split weights][rA][rC]
    constexpr int QKV_WN  = 1152 * 384;
    constexpr int PROJ_WN = 384 * 384;
    constexpr int FC1_WN  = 1536 * 384;
    constexpr int FC2_WN  = 384 * 1536;
    bf16* qh   = (bf16*)d_ws;
    bf16* ql   = qh  + QKV_WN;
    bf16* ph   = ql  + QKV_WN;
    bf16* pl   = ph  + PROJ_WN;
    bf16* f1h  = pl  + PROJ_WN;
    bf16* f1l  = f1h + FC1_WN;
    bf16* f2h  = f1l + FC1_WN;
    bf16* f2l  = f2h + FC2_WN;
    bf16* rA   = f2l + FC2_WN;
    bf16* rC   = rA + (size_t)NELEM;
    size_t used    = (size_t)((char*)rC - (char*)d_ws);
    size_t rCbytes = (ws_size > used) ? ws_size - used : 0;

    // 0. split weights + fused bias/mask table (btab lives in d_out upper half)
    cvt_split<<<(QKV_WN  + 255) / 256, 256, 0, stream>>>(qkv_w,  qh,  ql,  QKV_WN);
    cvt_split<<<(PROJ_WN + 255) / 256, 256, 0, stream>>>(proj_w, ph,  pl,  PROJ_WN);
    cvt_split<<<(FC1_WN  + 255) / 256, 256, 0, stream>>>(fc1_w,  f1h, f1l, FC1_WN);
    cvt_split<<<(FC2_WN  + 255) / 256, 256, 0, stream>>>(fc2_w,  f2h, f2l, FC2_WN);
    bias_precomp<<<96, 256, 0, stream>>>(rpb, btab);

    // adaptive grouping
    int W = 512;
    while (W > 1 && (size_t)W * 98 * 1152 * 2 > rCbytes) W >>= 1;
    int nqg = 512 / W;
    int ngm = 1;
    while (ngm < 1024 && (size_t)(TOK / ngm) * 1536 * 2 > rCbytes) ngm <<= 1;
    int Mt = TOK / ngm;

    dim3 blk(256);

    // 1. LN1 + shift + window partition: x -> rA (window-token order, bf16)
    ln_kernel<true><<<dim3(TOK / 4), blk, 0, stream>>>(x, n1w, n1b, rA);
    // 2. per group: QKV GEMM -> rC (bf16), attention -> aout (bf16)
    for (int g = 0; g < nqg; ++g) {
        int Mg = W * 98;
        gemm_mfma<0, bf16, float><<<dim3(1152 / 128, (Mg + 127) / 128), blk, 0, stream>>>(
            rA + (size_t)g * Mg * 384, 384, qh, ql, 384, qkv_b,
            rC, 1152, (const float*)nullptr, Mg, 384);
        attn_kernel<<<dim3(W * 12), dim3(64), 0, stream>>>(rC, btab, aout, g * W);
    }
    // 3. proj + window-reverse + roll + residual(x): aout -> rA (x1, bf16)
    gemm_mfma<1, bf16, float><<<dim3(384 / 128, TOK / 128), blk, 0, stream>>>(
        aout, 384, ph, pl, 384, proj_b, rA, 384, x, TOK, 384);
    // 4. LN2(x1=rA) -> xn2 (bf16, upper half of d_out; overwrites dead btab)
    ln_kernel<false><<<dim3(TOK / 4), blk, 0, stream>>>(rA, n2w, n2b, xn2);
    // 5. MLP per token group: fc1+gelu -> rC (bf16 hid), fc2 + x1 residual -> fout (fp32 final)
    for (int g = 0; g < ngm; ++g) {
        size_t off = (size_t)g * Mt * 384;
        gemm_mfma<2, bf16, float><<<dim3(1536 / 128, (Mt + 127) / 128), blk, 0, stream>>>(
            xn2 + off, 384, f1h, f1l, 384, fc1_b, rC, 1536, (const float*)nullptr, Mt, 384);
        gemm_mfma<4, float, bf16><<<dim3(384 / 128, (Mt + 127) / 128), blk, 0, stream>>>(
            rC, 1536, f2h, f2l, 1536, fc2_b, fout + off, 384, rA + off, Mt, 1536);
    }
}